// Round 1
// baseline (411.634 us; speedup 1.0000x reference)
//
#include <hip/hip_runtime.h>
#include <hip/hip_bf16.h>
#include <math.h>

#define B_   32
#define S_   512
#define D_   768
#define C_   128   // MAX_CHUNK_NUMBER
#define LCK  8     // MAX_CHUNK_LEN

// ---------------- Kernel 1: per-batch scan of chunk_lens -> starts, Tb ----------------
__global__ void scan_kernel(const int* __restrict__ lens, int* __restrict__ starts,
                            int* __restrict__ Tb) {
    int b = blockIdx.x;
    int t = threadIdx.x;           // 0..127
    __shared__ int s[C_];
    int v = lens[b * C_ + t];
    s[t] = v;
    __syncthreads();
    for (int off = 1; off < C_; off <<= 1) {
        int add = (t >= off) ? s[t - off] : 0;
        __syncthreads();
        s[t] += add;
        __syncthreads();
    }
    starts[b * C_ + t] = s[t] - v;   // exclusive prefix
    if (t == C_ - 1) Tb[b] = s[C_ - 1];
}

// ---------------- Kernel 1b: Lc = sum_e q[e]*tanh(dense_b[e]+attn_bias[e]) ----------------
__global__ void lc_kernel(const float* __restrict__ db, const float* __restrict__ ab,
                          const float* __restrict__ q, float* __restrict__ Lc) {
    int tid = threadIdx.x;
    float p = 0.f;
    for (int e = tid; e < D_; e += 256) p += tanhf(db[e] + ab[e]) * q[e];
    __shared__ float r[256];
    r[tid] = p;
    __syncthreads();
    for (int off = 128; off > 0; off >>= 1) {
        if (tid < off) r[tid] += r[tid + off];
        __syncthreads();
    }
    if (tid == 0) *Lc = r[0];
}

// ---------------- Kernel 2: fused GEMM + tanh + dot(query) -> partial logits ----------------
// logit[b,t] = sum_e q[e] * tanh( sum_d X[b,t,d]*W[e,d] + db[e]+ab[e] )
// Grid: (8 row-tiles of 64, 32 batches, 4 col-groups of 192 cols). Early-exit past Tb.
#define TM 64
#define TN 64
#define TK 32
#define NG 4
__global__ __launch_bounds__(256) void logits_gemm(
        const float* __restrict__ X, const float* __restrict__ W,
        const float* __restrict__ db, const float* __restrict__ ab,
        const float* __restrict__ q, const int* __restrict__ Tb,
        float* __restrict__ partial) {
    int b = blockIdx.y, z = blockIdx.z;
    int m0 = blockIdx.x * TM;
    if (m0 >= Tb[b]) return;

    __shared__ float Xs[TK][TM + 4];
    __shared__ float Ws[TK][TN + 4];
    __shared__ float red[TM][17];

    int tid = threadIdx.x;
    int tx = tid & 15, ty = tid >> 4;
    const float* Xb = X + (size_t)b * S_ * D_;

    float lsum[4] = {0.f, 0.f, 0.f, 0.f};

    for (int ci = 0; ci < 3; ++ci) {
        int e0 = (z * 3 + ci) * TN;
        float acc[4][4] = {};
        for (int k0 = 0; k0 < D_; k0 += TK) {
            // stage X tile (64 rows x 32 k) and W tile (64 e x 32 k), transposed into LDS
            #pragma unroll
            for (int p = 0; p < 2; ++p) {
                int idx = tid + p * 256;        // 0..511
                int row = idx >> 3;             // 0..63
                int kq  = (idx & 7) << 2;       // 0,4,..,28
                float4 xv = *(const float4*)(Xb + (size_t)(m0 + row) * D_ + k0 + kq);
                Xs[kq + 0][row] = xv.x; Xs[kq + 1][row] = xv.y;
                Xs[kq + 2][row] = xv.z; Xs[kq + 3][row] = xv.w;
                float4 wv = *(const float4*)(W + (size_t)(e0 + row) * D_ + k0 + kq);
                Ws[kq + 0][row] = wv.x; Ws[kq + 1][row] = wv.y;
                Ws[kq + 2][row] = wv.z; Ws[kq + 3][row] = wv.w;
            }
            __syncthreads();
            #pragma unroll
            for (int k = 0; k < TK; ++k) {
                float4 av = *(const float4*)&Xs[k][ty * 4];
                float4 bv = *(const float4*)&Ws[k][tx * 4];
                float a_[4] = {av.x, av.y, av.z, av.w};
                float b_[4] = {bv.x, bv.y, bv.z, bv.w};
                #pragma unroll
                for (int i = 0; i < 4; ++i)
                    #pragma unroll
                    for (int j = 0; j < 4; ++j)
                        acc[i][j] += a_[i] * b_[j];
            }
            __syncthreads();
        }
        // epilogue for this 64-col tile: tanh + dot with query
        #pragma unroll
        for (int j = 0; j < 4; ++j) {
            int e = e0 + tx * 4 + j;
            float beta = db[e] + ab[e];
            float qe = q[e];
            #pragma unroll
            for (int i = 0; i < 4; ++i)
                lsum[i] += tanhf(acc[i][j] + beta) * qe;
        }
    }

    // reduce lsum across the 16 tx-threads sharing the same rows
    __syncthreads();
    #pragma unroll
    for (int i = 0; i < 4; ++i) red[ty * 4 + i][tx] = lsum[i];
    __syncthreads();
    if (tid < TM) {
        float s = 0.f;
        #pragma unroll
        for (int x = 0; x < 16; ++x) s += red[tid][x];
        partial[((size_t)z * B_ + b) * S_ + m0 + tid] = s;
    }
}

// ---------------- Kernel 3: per-chunk softmax + weighted sum + LayerNorm ----------------
__global__ __launch_bounds__(256) void chunk_kernel(
        const float* __restrict__ X, const int* __restrict__ lens,
        const int* __restrict__ starts, const float* __restrict__ partial,
        const float* __restrict__ Lcp, const float* __restrict__ lnw,
        const float* __restrict__ lnb, float* __restrict__ cf) {
    int c = blockIdx.x, b = blockIdx.y, tid = threadIdx.x;
    int len = lens[b * C_ + c];
    len = max(0, min(len, LCK));
    int start = starts[b * C_ + c];
    float Lc = *Lcp;

    // logits for all 8 slots (invalid slots = Lc)
    float lg[LCK];
    #pragma unroll
    for (int l = 0; l < LCK; ++l) {
        bool valid = l < len;
        int t = valid ? (start + l) : start;      // safe address; value masked below
        float v = partial[((size_t)0 * B_ + b) * S_ + t]
                + partial[((size_t)1 * B_ + b) * S_ + t]
                + partial[((size_t)2 * B_ + b) * S_ + t]
                + partial[((size_t)3 * B_ + b) * S_ + t];
        lg[l] = valid ? v : Lc;
    }
    float m = lg[0];
    #pragma unroll
    for (int l = 1; l < LCK; ++l) m = fmaxf(m, lg[l]);
    float denom = 0.f;
    #pragma unroll
    for (int l = 0; l < LCK; ++l) { lg[l] = expf(lg[l] - m); denom += lg[l]; }
    float inv = 1.0f / denom;

    // weighted sum over valid tokens (invalid x-rows are zero in the reference)
    const float* Xb = X + (size_t)b * S_ * D_;
    float o[3];
    float sum = 0.f, sq = 0.f;
    #pragma unroll
    for (int kk = 0; kk < 3; ++kk) {
        int d = tid + kk * 256;
        float s = 0.f;
        #pragma unroll
        for (int l = 0; l < LCK; ++l) {
            if (l < len) s += lg[l] * Xb[(size_t)(start + l) * D_ + d];
        }
        s *= inv;
        o[kk] = s;
        sum += s;
        sq += s * s;
    }

    // block reduction for mean / var (4 waves of 64)
    #pragma unroll
    for (int off = 32; off > 0; off >>= 1) {
        sum += __shfl_down(sum, off);
        sq  += __shfl_down(sq, off);
    }
    __shared__ float rs[4], rq[4];
    int lane = tid & 63, wid = tid >> 6;
    if (lane == 0) { rs[wid] = sum; rq[wid] = sq; }
    __syncthreads();
    float tot  = rs[0] + rs[1] + rs[2] + rs[3];
    float totq = rq[0] + rq[1] + rq[2] + rq[3];
    float u = tot * (1.0f / D_);
    float var = totq * (1.0f / D_) - u * u;
    var = fmaxf(var, 0.0f);
    float rstd = rsqrtf(var + 1e-12f);

    float* out = cf + ((size_t)b * C_ + c) * D_;
    #pragma unroll
    for (int kk = 0; kk < 3; ++kk) {
        int d = tid + kk * 256;
        out[d] = lnw[d] * ((o[kk] - u) * rstd) + lnb[d];
    }
}

// ---------------- Kernel 4: sentence_embedding = max over 128 chunks ----------------
__global__ __launch_bounds__(256) void max_kernel(const float* __restrict__ cf,
                                                  float* __restrict__ sent) {
    int b = blockIdx.x;
    int d = blockIdx.y * 256 + threadIdx.x;
    const float* p = cf + (size_t)b * C_ * D_ + d;
    float m = -INFINITY;
    #pragma unroll 8
    for (int c = 0; c < C_; ++c) m = fmaxf(m, p[(size_t)c * D_]);
    sent[(size_t)b * D_ + d] = m;
}

extern "C" void kernel_launch(void* const* d_in, const int* in_sizes, int n_in,
                              void* d_out, int out_size, void* d_ws, size_t ws_size,
                              hipStream_t stream) {
    const float* X   = (const float*)d_in[0];  // tokens (32,512,768)
    const int*   ln_ = (const int*)d_in[1];    // chunk_lens (32,128)
    const float* W   = (const float*)d_in[2];  // dense_w (768,768)
    const float* db  = (const float*)d_in[3];  // dense_b (768)
    const float* ab  = (const float*)d_in[4];  // attn_bias (768)
    const float* q   = (const float*)d_in[5];  // query (768)
    const float* lnw = (const float*)d_in[6];  // ln_w (768)
    const float* lnb = (const float*)d_in[7];  // ln_b (768)

    float* cf   = (float*)d_out;                       // (32,128,768)
    float* sent = cf + (size_t)B_ * C_ * D_;           // (32,768)

    int*   starts  = (int*)d_ws;                       // 16 KB
    int*   Tb      = (int*)((char*)d_ws + 16384);      // 128 B
    float* Lc      = (float*)((char*)d_ws + 16640);    // 4 B
    float* partial = (float*)((char*)d_ws + 32768);    // 4*32*512*4 = 256 KB

    scan_kernel<<<B_, C_, 0, stream>>>(ln_, starts, Tb);
    lc_kernel<<<1, 256, 0, stream>>>(db, ab, q, Lc);
    dim3 g2(S_ / TM, B_, NG);
    logits_gemm<<<g2, 256, 0, stream>>>(X, W, db, ab, q, Tb, partial);
    dim3 g3(C_, B_);
    chunk_kernel<<<g3, 256, 0, stream>>>(X, ln_, starts, partial, Lc, lnw, lnb, cf);
    dim3 g4(B_, 3);
    max_kernel<<<g4, 256, 0, stream>>>(cf, sent);
}

// Round 3
// 192.908 us; speedup vs baseline: 2.1338x; 2.1338x over previous
//
#include <hip/hip_runtime.h>
#include <hip/hip_bf16.h>
#include <math.h>

#define B_   32
#define S_   512
#define D_   768
#define C_   128   // MAX_CHUNK_NUMBER
#define LCK  8     // MAX_CHUNK_LEN

#define MT   64    // block tile M
#define NT   128   // block tile N
#define KT   64    // K step
#define NGZ  6     // N groups: 768 / 128

typedef _Float16 half8_t __attribute__((ext_vector_type(8)));
typedef _Float16 half4_t __attribute__((ext_vector_type(4)));
typedef float    f32x4   __attribute__((ext_vector_type(4)));

// ---------------- Kernel 1: per-batch scan of chunk_lens -> starts, Tb ----------------
__global__ void scan_kernel(const int* __restrict__ lens, int* __restrict__ starts,
                            int* __restrict__ Tb) {
    int b = blockIdx.x;
    int t = threadIdx.x;           // 0..127
    __shared__ int s[C_];
    int v = lens[b * C_ + t];
    s[t] = v;
    __syncthreads();
    for (int off = 1; off < C_; off <<= 1) {
        int add = (t >= off) ? s[t - off] : 0;
        __syncthreads();
        s[t] += add;
        __syncthreads();
    }
    starts[b * C_ + t] = s[t] - v;   // exclusive prefix
    if (t == C_ - 1) Tb[b] = s[C_ - 1];
}

// ---------------- Kernel 1b: Lc = sum_e q[e]*tanh(dense_b[e]+attn_bias[e]) ----------------
__global__ void lc_kernel(const float* __restrict__ db, const float* __restrict__ ab,
                          const float* __restrict__ q, float* __restrict__ Lc) {
    int tid = threadIdx.x;
    float p = 0.f;
    for (int e = tid; e < D_; e += 256) p += tanhf(db[e] + ab[e]) * q[e];
    __shared__ float r[256];
    r[tid] = p;
    __syncthreads();
    for (int off = 128; off > 0; off >>= 1) {
        if (tid < off) r[tid] += r[tid + off];
        __syncthreads();
    }
    if (tid == 0) *Lc = r[0];
}

// ---------------- Kernel 1c: split W (fp32) -> Whi, Wlo (fp16) ----------------
__global__ __launch_bounds__(256) void wsplit_kernel(const float* __restrict__ W,
                                                     _Float16* __restrict__ hi,
                                                     _Float16* __restrict__ lo) {
    int i = (blockIdx.x * 256 + threadIdx.x) * 4;
    float4 w = *(const float4*)(W + i);
    float wf[4] = {w.x, w.y, w.z, w.w};
    half4_t h, l;
    #pragma unroll
    for (int j = 0; j < 4; ++j) {
        _Float16 hh = (_Float16)wf[j];
        h[j] = hh;
        l[j] = (_Float16)(wf[j] - (float)hh);
    }
    *(half4_t*)(hi + i) = h;
    *(half4_t*)(lo + i) = l;
}

// ---------------- Kernel 2: MFMA GEMM + tanh + dot(query) -> partial logits ----------------
// logit[b,t] = sum_e q[e] * tanh( sum_d X[b,t,d]*W[e,d] + db[e]+ab[e] )
// fp16-split: X ~ fp16, W = Whi + Wlo (fp16); preact accumulated in fp32 via 2 MFMA passes.
// A-frag (16x16x32): lane l holds A[l&15][(l>>4)*8 + j], j=0..7 (8 contiguous k)
// B-frag:            lane l holds B[l&15][(l>>4)*8 + j]  (W row-major, k contiguous)
// C/D: col = lane&15, row = (lane>>4)*4 + reg   [m89-verified]
__global__ __launch_bounds__(256, 4) void logits_mfma(
        const float* __restrict__ X,
        const _Float16* __restrict__ Whf, const _Float16* __restrict__ Wlf,
        const float* __restrict__ db, const float* __restrict__ ab,
        const float* __restrict__ q, const int* __restrict__ Tb,
        float* __restrict__ partial) {
    int b = blockIdx.y, z = blockIdx.z;
    int m0 = blockIdx.x * MT;
    if (m0 >= Tb[b]) return;
    int e0 = z * NT;

    __shared__ _Float16 As[MT * KT];   // [row][64] halves, XOR-swizzled, 8 KB
    __shared__ _Float16 Bh[NT * KT];   // 16 KB
    __shared__ _Float16 Bl[NT * KT];   // 16 KB

    int tid = threadIdx.x;
    int lane = tid & 63, wid = tid >> 6;
    int wm = wid >> 1, wn = wid & 1;   // wave tile: rows wm*32, cols wn*64

    const float* Xb = X + (size_t)b * S_ * D_;

    f32x4 acc[2][4];
    #pragma unroll
    for (int mt = 0; mt < 2; ++mt)
        #pragma unroll
        for (int nt = 0; nt < 4; ++nt)
            acc[mt][nt] = (f32x4)(0.0f);

    for (int k0 = 0; k0 < D_; k0 += KT) {
        // ---- stage X tile (64 rows x 64 k), fp32 -> fp16, swizzled ----
        #pragma unroll
        for (int p = 0; p < 2; ++p) {
            int idx = tid + p * 256;        // 0..511
            int row = idx >> 3;             // 0..63
            int ks  = idx & 7;              // 16B segment within row
            const float* src = Xb + (size_t)(m0 + row) * D_ + k0 + ks * 8;
            float4 f0 = *(const float4*)src;
            float4 f1 = *(const float4*)(src + 4);
            half8_t h;
            h[0] = (_Float16)f0.x; h[1] = (_Float16)f0.y;
            h[2] = (_Float16)f0.z; h[3] = (_Float16)f0.w;
            h[4] = (_Float16)f1.x; h[5] = (_Float16)f1.y;
            h[6] = (_Float16)f1.z; h[7] = (_Float16)f1.w;
            int byte = (row << 7) + (ks << 4);
            byte ^= (row & 7) << 4;
            *(half8_t*)((char*)As + byte) = h;
        }
        // ---- stage W hi/lo tiles (128 rows x 64 k each), already fp16 ----
        #pragma unroll
        for (int p = 0; p < 4; ++p) {
            int idx = tid + p * 256;        // 0..1023
            int row = idx >> 3;             // 0..127
            int ks  = idx & 7;
            size_t goff = (size_t)(e0 + row) * D_ + k0 + ks * 8;
            half8_t h = *(const half8_t*)(Whf + goff);
            half8_t l = *(const half8_t*)(Wlf + goff);
            int byte = (row << 7) + (ks << 4);
            byte ^= (row & 7) << 4;
            *(half8_t*)((char*)Bh + byte) = h;
            *(half8_t*)((char*)Bl + byte) = l;
        }
        __syncthreads();

        // ---- MFMA: 2 k-subtiles of 32, 2 passes (hi, lo) ----
        #pragma unroll
        for (int ksub = 0; ksub < 2; ++ksub) {
            half8_t a[2];
            #pragma unroll
            for (int mt = 0; mt < 2; ++mt) {
                int row = wm * 32 + mt * 16 + (lane & 15);
                int byte = (row << 7) + (ksub << 6) + ((lane >> 4) << 4);
                byte ^= (row & 7) << 4;
                a[mt] = *(const half8_t*)((const char*)As + byte);
            }
            #pragma unroll
            for (int nt = 0; nt < 4; ++nt) {
                int row = wn * 64 + nt * 16 + (lane & 15);
                int byte = (row << 7) + (ksub << 6) + ((lane >> 4) << 4);
                byte ^= (row & 7) << 4;
                half8_t bh = *(const half8_t*)((const char*)Bh + byte);
                half8_t bl = *(const half8_t*)((const char*)Bl + byte);
                #pragma unroll
                for (int mt = 0; mt < 2; ++mt) {
                    acc[mt][nt] = __builtin_amdgcn_mfma_f32_16x16x32_f16(a[mt], bh, acc[mt][nt], 0, 0, 0);
                    acc[mt][nt] = __builtin_amdgcn_mfma_f32_16x16x32_f16(a[mt], bl, acc[mt][nt], 0, 0, 0);
                }
            }
        }
        __syncthreads();
    }

    // ---- epilogue: tanh + q-dot, reduce over this block's 128 cols ----
    float lsum[2][4];
    #pragma unroll
    for (int mt = 0; mt < 2; ++mt)
        #pragma unroll
        for (int r = 0; r < 4; ++r) lsum[mt][r] = 0.f;

    #pragma unroll
    for (int nt = 0; nt < 4; ++nt) {
        int e = e0 + wn * 64 + nt * 16 + (lane & 15);
        float beta = db[e] + ab[e];
        float qe = q[e];
        #pragma unroll
        for (int mt = 0; mt < 2; ++mt)
            #pragma unroll
            for (int r = 0; r < 4; ++r)
                lsum[mt][r] += tanhf(acc[mt][nt][r] + beta) * qe;
    }
    // reduce over the 16 lanes holding different cols of the same rows
    #pragma unroll
    for (int off = 1; off < 16; off <<= 1)
        #pragma unroll
        for (int mt = 0; mt < 2; ++mt)
            #pragma unroll
            for (int r = 0; r < 4; ++r)
                lsum[mt][r] += __shfl_xor(lsum[mt][r], off, 64);

    // combine the two wn halves via LDS (reuse As)
    float* rsum = (float*)As;   // 64 rows x 2
    if ((lane & 15) == 0) {
        #pragma unroll
        for (int mt = 0; mt < 2; ++mt)
            #pragma unroll
            for (int r = 0; r < 4; ++r)
                rsum[(wm * 32 + mt * 16 + (lane >> 4) * 4 + r) * 2 + wn] = lsum[mt][r];
    }
    __syncthreads();
    if (tid < MT)
        partial[((size_t)z * B_ + b) * S_ + m0 + tid] = rsum[tid * 2] + rsum[tid * 2 + 1];
}

// ---------------- Kernel 3: per-chunk softmax + weighted sum + LayerNorm ----------------
__global__ __launch_bounds__(256) void chunk_kernel(
        const float* __restrict__ X, const int* __restrict__ lens,
        const int* __restrict__ starts, const float* __restrict__ partial,
        const float* __restrict__ Lcp, const float* __restrict__ lnw,
        const float* __restrict__ lnb, float* __restrict__ cf) {
    int c = blockIdx.x, b = blockIdx.y, tid = threadIdx.x;
    int len = lens[b * C_ + c];
    len = max(0, min(len, LCK));
    int start = starts[b * C_ + c];
    float Lc = *Lcp;

    // logits for all 8 slots (invalid slots = Lc)
    float lg[LCK];
    #pragma unroll
    for (int l = 0; l < LCK; ++l) {
        bool valid = l < len;
        int t = valid ? (start + l) : start;   // safe address; value masked below
        float v = 0.f;
        #pragma unroll
        for (int zz = 0; zz < NGZ; ++zz)
            v += partial[((size_t)zz * B_ + b) * S_ + t];
        lg[l] = valid ? v : Lc;
    }
    float m = lg[0];
    #pragma unroll
    for (int l = 1; l < LCK; ++l) m = fmaxf(m, lg[l]);
    float denom = 0.f;
    #pragma unroll
    for (int l = 0; l < LCK; ++l) { lg[l] = expf(lg[l] - m); denom += lg[l]; }
    float inv = 1.0f / denom;

    // weighted sum over valid tokens (invalid x-rows are zero in the reference)
    const float* Xb = X + (size_t)b * S_ * D_;
    float o[3];
    float sum = 0.f, sq = 0.f;
    #pragma unroll
    for (int kk = 0; kk < 3; ++kk) {
        int d = tid + kk * 256;
        float s = 0.f;
        #pragma unroll
        for (int l = 0; l < LCK; ++l) {
            if (l < len) s += lg[l] * Xb[(size_t)(start + l) * D_ + d];
        }
        s *= inv;
        o[kk] = s;
        sum += s;
        sq += s * s;
    }

    // block reduction for mean / var (4 waves of 64)
    #pragma unroll
    for (int off = 32; off > 0; off >>= 1) {
        sum += __shfl_down(sum, off);
        sq  += __shfl_down(sq, off);
    }
    __shared__ float rs[4], rq[4];
    int lane = tid & 63, wid = tid >> 6;
    if (lane == 0) { rs[wid] = sum; rq[wid] = sq; }
    __syncthreads();
    float tot  = rs[0] + rs[1] + rs[2] + rs[3];
    float totq = rq[0] + rq[1] + rq[2] + rq[3];
    float u = tot * (1.0f / D_);
    float var = totq * (1.0f / D_) - u * u;
    var = fmaxf(var, 0.0f);
    float rstd = rsqrtf(var + 1e-12f);

    float* out = cf + ((size_t)b * C_ + c) * D_;
    #pragma unroll
    for (int kk = 0; kk < 3; ++kk) {
        int d = tid + kk * 256;
        out[d] = lnw[d] * ((o[kk] - u) * rstd) + lnb[d];
    }
}

// ---------------- Kernel 4: sentence_embedding = max over 128 chunks ----------------
__global__ __launch_bounds__(256) void max_kernel(const float* __restrict__ cf,
                                                  float* __restrict__ sent) {
    int b = blockIdx.x;
    int d = blockIdx.y * 256 + threadIdx.x;
    const float* p = cf + (size_t)b * C_ * D_ + d;
    float m = -INFINITY;
    #pragma unroll 8
    for (int c = 0; c < C_; ++c) m = fmaxf(m, p[(size_t)c * D_]);
    sent[(size_t)b * D_ + d] = m;
}

extern "C" void kernel_launch(void* const* d_in, const int* in_sizes, int n_in,
                              void* d_out, int out_size, void* d_ws, size_t ws_size,
                              hipStream_t stream) {
    const float* X   = (const float*)d_in[0];  // tokens (32,512,768)
    const int*   ln_ = (const int*)d_in[1];    // chunk_lens (32,128)
    const float* W   = (const float*)d_in[2];  // dense_w (768,768)
    const float* db  = (const float*)d_in[3];  // dense_b (768)
    const float* ab  = (const float*)d_in[4];  // attn_bias (768)
    const float* q   = (const float*)d_in[5];  // query (768)
    const float* lnw = (const float*)d_in[6];  // ln_w (768)
    const float* lnb = (const float*)d_in[7];  // ln_b (768)

    float* cf   = (float*)d_out;                       // (32,128,768)
    float* sent = cf + (size_t)B_ * C_ * D_;           // (32,768)

    // workspace layout (all 16B-aligned)
    int*      starts  = (int*)d_ws;                                   // 16 KB
    int*      Tb      = (int*)((char*)d_ws + 16384);                  // 128 B
    float*    Lc      = (float*)((char*)d_ws + 16640);                // 4 B
    _Float16* Whf     = (_Float16*)((char*)d_ws + 32768);             // 1.125 MB
    _Float16* Wlf     = (_Float16*)((char*)d_ws + 32768 + 1179648);   // 1.125 MB
    float*    partial = (float*)((char*)d_ws + 32768 + 2 * 1179648);  // 6*32*512*4 = 384 KB

    scan_kernel<<<B_, C_, 0, stream>>>(ln_, starts, Tb);
    lc_kernel<<<1, 256, 0, stream>>>(db, ab, q, Lc);
    wsplit_kernel<<<(D_ * D_) / (256 * 4), 256, 0, stream>>>(W, Whf, Wlf);

    dim3 g2(S_ / MT, B_, NGZ);
    logits_mfma<<<g2, 256, 0, stream>>>(X, Whf, Wlf, db, ab, q, Tb, partial);

    dim3 g3(C_, B_);
    chunk_kernel<<<g3, 256, 0, stream>>>(X, ln_, starts, partial, Lc, lnw, lnb, cf);
    dim3 g4(B_, 3);
    max_kernel<<<g4, 256, 0, stream>>>(cf, sent);
}